// Round 6
// baseline (158.185 us; speedup 1.0000x reference)
//
#include <hip/hip_runtime.h>
#include <math.h>

static constexpr int TPB   = 256;
static constexpr int SUB   = 8;            // members per sub-chunk
static constexpr int NSUB  = 4;            // sub-chunks per thread-iteration
static constexpr int TCHUNK = SUB * NSUB;  // 32 members per thread-iteration
static constexpr int SBLK  = 958;          // seg worker blocks
static constexpr int MBLK  = 1042;         // mlp worker blocks (total 2000 <= 2048 resident)

// ---------------------------------------------------------------------------
// Workspace zero (rocclr fillBufferAligned is slow for small fills).
// ---------------------------------------------------------------------------
__global__ __launch_bounds__(256)
void zero_ws_kernel(float4* __restrict__ ws, int n4) {
  int i = blockIdx.x * blockDim.x + threadIdx.x;
  int stride = gridDim.x * blockDim.x;
  for (; i < n4; i += stride) ws[i] = make_float4(0.f, 0.f, 0.f, 0.f);
}

// ---------------------------------------------------------------------------
// Fused persistent kernel, barrier-free.
//  seg role  (blocks [0,SBLK)): grid-stride over 32-member tiles; run-length
//    scan in registers; flush each run with fire-and-forget unsafeAtomicAdd
//    (global HW fp atomic, no return -> no wait). No LDS, no __syncthreads:
//    loop iterations software-pipeline into a continuous load stream.
//  mlp role  (blocks [SBLK,SBLK+MBLK)): persistent waves, grid-stride over
//    row-quads (4 rows/wave, 16 lanes/row, 4xfloat4/lane) so iteration k+1
//    loads issue under iteration k compute.
// ---------------------------------------------------------------------------
__global__ __launch_bounds__(TPB)
void fused_kernel(const float* __restrict__ lm,
                  const float* __restrict__ pos,
                  const int*   __restrict__ idx,
                  const float* __restrict__ gf,
                  const float* __restrict__ w,
                  const float* __restrict__ bptr,
                  const float* __restrict__ noise,
                  const int*   __restrict__ temp_ptr,
                  float* __restrict__ seg_sum,     // [G]
                  float* __restrict__ center_raw,  // [3G]
                  float* __restrict__ out,         // [5G]
                  int M, int G) {
  if (blockIdx.x < SBLK) {
    // ---------------- seg role ----------------
    auto flush = [&](int g, float se, float sx, float sy, float sz) {
      unsafeAtomicAdd(&seg_sum[g], se);
      unsafeAtomicAdd(&center_raw[3*g+0], sx);
      unsafeAtomicAdd(&center_raw[3*g+1], sy);
      unsafeAtomicAdd(&center_raw[3*g+2], sz);
    };

    int NT = (M + TCHUNK - 1) / TCHUNK;           // 32-member tiles
    int sid = blockIdx.x * TPB + threadIdx.x;
    int sstride = SBLK * TPB;

    for (int t = sid; t < NT; t += sstride) {
      int mb = t * TCHUNK;
      if (mb + TCHUNK <= M) {
        int cur = -1;
        float se = 0.f, sx = 0.f, sy = 0.f, sz = 0.f;
        #pragma unroll
        for (int s = 0; s < NSUB; s++) {
          int b = mb + s * SUB;
          const int4*   i4 = (const int4*)(idx + b);
          const float4* l4 = (const float4*)(lm + b);
          const float4* p4 = (const float4*)(pos + (size_t)b * 3);
          int4 ia = i4[0], ic = i4[1];
          float4 la = l4[0], lc = l4[1];
          float4 pA = p4[0], pB = p4[1], pC = p4[2],
                 pD = p4[3], pE = p4[4], pF = p4[5];
          int   ib[SUB] = {ia.x,ia.y,ia.z,ia.w, ic.x,ic.y,ic.z,ic.w};
          float eb[SUB];
          eb[0]=__expf(la.x); eb[1]=__expf(la.y); eb[2]=__expf(la.z); eb[3]=__expf(la.w);
          eb[4]=__expf(lc.x); eb[5]=__expf(lc.y); eb[6]=__expf(lc.z); eb[7]=__expf(lc.w);
          float pb[SUB*3] = {pA.x,pA.y,pA.z,pA.w, pB.x,pB.y,pB.z,pB.w,
                             pC.x,pC.y,pC.z,pC.w, pD.x,pD.y,pD.z,pD.w,
                             pE.x,pE.y,pE.z,pE.w, pF.x,pF.y,pF.z,pF.w};
          if (s == 0) cur = ib[0];
          #pragma unroll
          for (int j = 0; j < SUB; j++) {
            if (ib[j] != cur) {
              flush(cur, se, sx, sy, sz);
              cur = ib[j]; se = 0.f; sx = 0.f; sy = 0.f; sz = 0.f;
            }
            se += eb[j];
            sx += pb[3*j+0] * eb[j];
            sy += pb[3*j+1] * eb[j];
            sz += pb[3*j+2] * eb[j];
          }
        }
        flush(cur, se, sx, sy, sz);
      } else {
        // tail tile (partial)
        int nj = M - mb;
        if (nj <= 0) continue;
        int cur = idx[mb];
        float se = 0.f, sx = 0.f, sy = 0.f, sz = 0.f;
        for (int j = 0; j < nj; j++) {
          int g = idx[mb + j];
          float e = __expf(lm[mb + j]);
          if (g != cur) {
            flush(cur, se, sx, sy, sz);
            cur = g; se = 0.f; sx = 0.f; sy = 0.f; sz = 0.f;
          }
          se += e;
          sx += pos[(size_t)(mb+j)*3+0] * e;
          sy += pos[(size_t)(mb+j)*3+1] * e;
          sz += pos[(size_t)(mb+j)*3+2] * e;
        }
        flush(cur, se, sx, sy, sz);
      }
    }
  } else {
    // ---------------- mlp role ----------------
    int wid  = threadIdx.x >> 6;
    int lane = threadIdx.x & 63;
    int sub  = lane & 15;        // lane within 16-lane row group
    int rg   = lane >> 4;        // row within quad

    int NQ = (G + 3) / 4;                          // row-quads
    int wv = (int)(blockIdx.x - SBLK) * 4 + wid;   // global mlp wave id
    int wstride = MBLK * 4;

    float bb = bptr[0];
    int iv = temp_ptr[0];
    float tT = (iv > -(1 << 23) && iv < (1 << 23)) ? (float)iv : __int_as_float(iv);
    const float4* w4 = (const float4*)w;
    float4 wv0 = w4[sub +  0], wv1 = w4[sub + 16],
           wv2 = w4[sub + 32], wv3 = w4[sub + 48];

    for (int q = wv; q < NQ; q += wstride) {
      int row = q * 4 + rg;
      float d = 0.f;
      if (row < G) {
        const float4* grow = (const float4*)(gf + (size_t)row * 256);
        float4 g0 = grow[sub +  0], g1 = grow[sub + 16],
               g2 = grow[sub + 32], g3 = grow[sub + 48];
        d  = g0.x*wv0.x + g0.y*wv0.y + g0.z*wv0.z + g0.w*wv0.w;
        d += g1.x*wv1.x + g1.y*wv1.y + g1.z*wv1.z + g1.w*wv1.w;
        d += g2.x*wv2.x + g2.y*wv2.y + g2.z*wv2.z + g2.w*wv2.w;
        d += g3.x*wv3.x + g3.y*wv3.y + g3.z*wv3.z + g3.w*wv3.w;
      }
      #pragma unroll
      for (int m = 8; m >= 1; m >>= 1) d += __shfl_xor(d, m, 64);

      if (sub == 0 && row < G) {
        float logit = 8.8f * tanhf(d + bb);
        float n = noise[row];
        float logistic = logf(n) - log1pf(-n);
        float x = (logit + logistic) / tT;
        float lz = fminf(x, 0.f) - log1pf(expf(-fabsf(x)));
        out[row]     = lz;
        out[G + row] = logit;
      }
    }
  }
}

// ---------------------------------------------------------------------------
// Center normalize: out[2G + i] = center_raw[i] / seg_sum[i/3] (0 if empty).
// ---------------------------------------------------------------------------
__global__ __launch_bounds__(256)
void norm_kernel(const float* __restrict__ seg_sum,
                 const float* __restrict__ center_raw,
                 float* __restrict__ out, int G) {
  int i = blockIdx.x * blockDim.x + threadIdx.x;
  int n = 3 * G;
  if (i < n) {
    int g = i / 3;
    float s = seg_sum[g];
    float inv = (s > 0.f) ? (1.f / s) : 0.f;
    out[(size_t)2 * G + i] = center_raw[i] * inv;
  }
}

extern "C" void kernel_launch(void* const* d_in, const int* in_sizes, int n_in,
                              void* d_out, int out_size, void* d_ws, size_t ws_size,
                              hipStream_t stream) {
  const float* gf    = (const float*)d_in[0];
  const float* pos   = (const float*)d_in[1];
  const float* lm    = (const float*)d_in[2];
  const int*   idx   = (const int*)  d_in[3];
  const float* w     = (const float*)d_in[4];
  const float* b     = (const float*)d_in[5];
  const float* noise = (const float*)d_in[6];
  const int*   temp  = (const int*)  d_in[7];
  float* out = (float*)d_out;

  int G = in_sizes[6];
  int M = in_sizes[3];

  float* seg_sum    = (float*)d_ws;
  float* center_raw = seg_sum + G;

  int n4 = (4 * G) / 4;
  hipLaunchKernelGGL(zero_ws_kernel, dim3(784), dim3(256), 0, stream,
                     (float4*)d_ws, n4);

  hipLaunchKernelGGL(fused_kernel, dim3(SBLK + MBLK), dim3(TPB), 0, stream,
                     lm, pos, idx, gf, w, b, noise, temp,
                     seg_sum, center_raw, out, M, G);

  int nblk = (3 * G + 255) / 256;
  hipLaunchKernelGGL(norm_kernel, dim3(nblk), dim3(256), 0, stream,
                     seg_sum, center_raw, out, G);
}

// Round 7
// 107.222 us; speedup vs baseline: 1.4753x; 1.4753x over previous
//
#include <hip/hip_runtime.h>
#include <math.h>

static constexpr int TPB   = 256;
static constexpr int CHUNK = 8;             // members per thread per tile
static constexpr int TILE  = TPB * CHUNK;   // 2048 members per tile
static constexpr int TPBLK = 5;             // tiles per seg block
static constexpr int MPB   = TILE * TPBLK;  // 10240 members per seg block
static constexpr int LOCAL_BINS = 448;      // expected span ~214 (+3sigma margin)

// ---------------------------------------------------------------------------
// Workspace zero (rocclr fillBufferAligned is slow for small fills).
// ---------------------------------------------------------------------------
__global__ __launch_bounds__(256)
void zero_ws_kernel(float4* __restrict__ ws, int n4) {
  int i = blockIdx.x * blockDim.x + threadIdx.x;
  int stride = gridDim.x * blockDim.x;
  for (; i < n4; i += stride) ws[i] = make_float4(0.f, 0.f, 0.f, 0.f);
}

// ---------------------------------------------------------------------------
// Fused kernel, Bresenham role interleave (seg : mlp = nseg : nmlp).
//
// seg role: 10240 contiguous members per block, LDS bins over the block's
//   segment span. Exactly 2 barriers per block (bin zero, flush) -- the
//   round-4 structure had 3 per 2048 members and stalled on vmcnt drains.
//   Interior segments -> plain global store (exclusive by sortedness);
//   2 edge segments -> HW fp atomic (~7.5k atomics total, vs 2M in round 6
//   whose line ping-pong cost +160MB FETCH / +41MB WRITE).
// mlp role: persistent waves, contiguous chunk of row-quads per wave
//   (4 rows/wave, 16 lanes/row), loads of quad q+1 issue under compute of q.
// ---------------------------------------------------------------------------
__global__ __launch_bounds__(TPB)
void fused_kernel(const float* __restrict__ lm,
                  const float* __restrict__ pos,
                  const int*   __restrict__ idx,
                  const float* __restrict__ gf,
                  const float* __restrict__ w,
                  const float* __restrict__ bptr,
                  const float* __restrict__ noise,
                  const int*   __restrict__ temp_ptr,
                  float* __restrict__ seg_sum,     // [G]
                  float* __restrict__ center_raw,  // [3G]
                  float* __restrict__ out,         // [5G]
                  int M, int G, int nseg, int ntot, int nmlp) {
  __shared__ float bins[LOCAL_BINS * 4];

  long long r = blockIdx.x;
  int segcum  = (int)((r * (long long)nseg) / ntot);
  int segcum1 = (int)(((r + 1) * (long long)nseg) / ntot);

  if (segcum1 != segcum) {
    // ---------------- seg role ----------------
    int blockStart = segcum * MPB;
    if (blockStart >= M) return;
    int blockEnd = min(blockStart + MPB, M);
    int g_first = idx[blockStart];
    int g_last  = idx[blockEnd - 1];
    int span    = g_last - g_first + 1;
    int nbins   = min(span, LOCAL_BINS);

    for (int i = threadIdx.x; i < nbins * 4; i += TPB) bins[i] = 0.f;
    __syncthreads();

    auto flush = [&](int g, float se, float sx, float sy, float sz) {
      int off = g - g_first;
      if (off < LOCAL_BINS) {
        unsafeAtomicAdd(&bins[off*4+0], se);
        unsafeAtomicAdd(&bins[off*4+1], sx);
        unsafeAtomicAdd(&bins[off*4+2], sy);
        unsafeAtomicAdd(&bins[off*4+3], sz);
      } else {               // span overflow fallback (statistically ~never)
        unsafeAtomicAdd(&seg_sum[g], se);
        unsafeAtomicAdd(&center_raw[3*g+0], sx);
        unsafeAtomicAdd(&center_raw[3*g+1], sy);
        unsafeAtomicAdd(&center_raw[3*g+2], sz);
      }
    };

    #pragma unroll
    for (int k = 0; k < TPBLK; k++) {
      int base = blockStart + k * TILE + threadIdx.x * CHUNK;
      if (base >= M) continue;
      if (base + CHUNK <= M) {
        const int4*   i4 = (const int4*)(idx + base);
        const float4* l4 = (const float4*)(lm + base);
        const float4* p4 = (const float4*)(pos + (size_t)base * 3);
        int4 ia = i4[0], ic = i4[1];
        float4 la = l4[0], lc = l4[1];
        float4 pA = p4[0], pB = p4[1], pC = p4[2],
               pD = p4[3], pE = p4[4], pF = p4[5];
        int   ib[CHUNK] = {ia.x,ia.y,ia.z,ia.w, ic.x,ic.y,ic.z,ic.w};
        float eb[CHUNK];
        eb[0]=__expf(la.x); eb[1]=__expf(la.y); eb[2]=__expf(la.z); eb[3]=__expf(la.w);
        eb[4]=__expf(lc.x); eb[5]=__expf(lc.y); eb[6]=__expf(lc.z); eb[7]=__expf(lc.w);
        float pb[CHUNK*3] = {pA.x,pA.y,pA.z,pA.w, pB.x,pB.y,pB.z,pB.w,
                             pC.x,pC.y,pC.z,pC.w, pD.x,pD.y,pD.z,pD.w,
                             pE.x,pE.y,pE.z,pE.w, pF.x,pF.y,pF.z,pF.w};

        if (ib[0] == ib[CHUNK-1]) {
          // fast path: whole chunk in one segment (prob ~exp(-8/48)~0.85)
          float se = 0.f, sx = 0.f, sy = 0.f, sz = 0.f;
          #pragma unroll
          for (int j = 0; j < CHUNK; j++) {
            se += eb[j];
            sx += pb[3*j+0] * eb[j];
            sy += pb[3*j+1] * eb[j];
            sz += pb[3*j+2] * eb[j];
          }
          flush(ib[0], se, sx, sy, sz);
        } else {
          int cur = ib[0];
          float se = 0.f, sx = 0.f, sy = 0.f, sz = 0.f;
          #pragma unroll
          for (int j = 0; j < CHUNK; j++) {
            if (ib[j] != cur) {
              flush(cur, se, sx, sy, sz);
              cur = ib[j]; se = 0.f; sx = 0.f; sy = 0.f; sz = 0.f;
            }
            se += eb[j];
            sx += pb[3*j+0] * eb[j];
            sy += pb[3*j+1] * eb[j];
            sz += pb[3*j+2] * eb[j];
          }
          flush(cur, se, sx, sy, sz);
        }
      } else {
        // ragged tail chunk
        int nj = M - base;
        int cur = idx[base];
        float se = 0.f, sx = 0.f, sy = 0.f, sz = 0.f;
        for (int j = 0; j < nj; j++) {
          int g = idx[base + j];
          float e = __expf(lm[base + j]);
          if (g != cur) {
            flush(cur, se, sx, sy, sz);
            cur = g; se = 0.f; sx = 0.f; sy = 0.f; sz = 0.f;
          }
          se += e;
          sx += pos[(size_t)(base+j)*3+0] * e;
          sy += pos[(size_t)(base+j)*3+1] * e;
          sz += pos[(size_t)(base+j)*3+2] * e;
        }
        flush(cur, se, sx, sy, sz);
      }
    }
    __syncthreads();

    for (int i = threadIdx.x; i < nbins; i += TPB) {
      int g = g_first + i;
      float s0 = bins[i*4+0], s1 = bins[i*4+1], s2 = bins[i*4+2], s3 = bins[i*4+3];
      if (g == g_first || g == g_last) {
        unsafeAtomicAdd(&seg_sum[g], s0);
        unsafeAtomicAdd(&center_raw[3*g+0], s1);
        unsafeAtomicAdd(&center_raw[3*g+1], s2);
        unsafeAtomicAdd(&center_raw[3*g+2], s3);
      } else {
        seg_sum[g] = s0;
        center_raw[3*g+0] = s1;
        center_raw[3*g+1] = s2;
        center_raw[3*g+2] = s3;
      }
    }
  } else {
    // ---------------- mlp role ----------------
    int mb   = (int)(r - segcum);
    int wid  = threadIdx.x >> 6;
    int lane = threadIdx.x & 63;
    int sub  = lane & 15;        // lane within 16-lane row group
    int rg   = lane >> 4;        // row within quad

    int NQ = (G + 3) / 4;
    int nwaves = nmlp * 4;
    int wvid = mb * 4 + wid;
    int qpw = (NQ + nwaves - 1) / nwaves;
    int q0 = wvid * qpw;
    int q1 = min(NQ, q0 + qpw);

    float bb = bptr[0];
    int iv = temp_ptr[0];
    float tT = (iv > -(1 << 23) && iv < (1 << 23)) ? (float)iv : __int_as_float(iv);
    const float4* w4 = (const float4*)w;
    float4 wv0 = w4[sub +  0], wv1 = w4[sub + 16],
           wv2 = w4[sub + 32], wv3 = w4[sub + 48];

    for (int q = q0; q < q1; q++) {
      int row = q * 4 + rg;
      float d = 0.f;
      if (row < G) {
        const float4* grow = (const float4*)(gf + (size_t)row * 256);
        float4 g0 = grow[sub +  0], g1 = grow[sub + 16],
               g2 = grow[sub + 32], g3 = grow[sub + 48];
        d  = g0.x*wv0.x + g0.y*wv0.y + g0.z*wv0.z + g0.w*wv0.w;
        d += g1.x*wv1.x + g1.y*wv1.y + g1.z*wv1.z + g1.w*wv1.w;
        d += g2.x*wv2.x + g2.y*wv2.y + g2.z*wv2.z + g2.w*wv2.w;
        d += g3.x*wv3.x + g3.y*wv3.y + g3.z*wv3.z + g3.w*wv3.w;
      }
      #pragma unroll
      for (int m = 8; m >= 1; m >>= 1) d += __shfl_xor(d, m, 64);

      if (sub == 0 && row < G) {
        float logit = 8.8f * tanhf(d + bb);
        float n = noise[row];
        float logistic = logf(n) - log1pf(-n);
        float x = (logit + logistic) / tT;
        float lz = fminf(x, 0.f) - log1pf(expf(-fabsf(x)));
        out[row]     = lz;
        out[G + row] = logit;
      }
    }
  }
}

// ---------------------------------------------------------------------------
// Center normalize: out[2G + i] = center_raw[i] / seg_sum[i/3] (0 if empty).
// ---------------------------------------------------------------------------
__global__ __launch_bounds__(256)
void norm_kernel(const float* __restrict__ seg_sum,
                 const float* __restrict__ center_raw,
                 float* __restrict__ out, int G) {
  int i = blockIdx.x * blockDim.x + threadIdx.x;
  int n = 3 * G;
  if (i < n) {
    int g = i / 3;
    float s = seg_sum[g];
    float inv = (s > 0.f) ? (1.f / s) : 0.f;
    out[(size_t)2 * G + i] = center_raw[i] * inv;
  }
}

extern "C" void kernel_launch(void* const* d_in, const int* in_sizes, int n_in,
                              void* d_out, int out_size, void* d_ws, size_t ws_size,
                              hipStream_t stream) {
  const float* gf    = (const float*)d_in[0];
  const float* pos   = (const float*)d_in[1];
  const float* lm    = (const float*)d_in[2];
  const int*   idx   = (const int*)  d_in[3];
  const float* w     = (const float*)d_in[4];
  const float* b     = (const float*)d_in[5];
  const float* noise = (const float*)d_in[6];
  const int*   temp  = (const int*)  d_in[7];
  float* out = (float*)d_out;

  int G = in_sizes[6];
  int M = in_sizes[3];

  float* seg_sum    = (float*)d_ws;
  float* center_raw = seg_sum + G;

  int n4 = (4 * G) / 4;
  hipLaunchKernelGGL(zero_ws_kernel, dim3(784), dim3(256), 0, stream,
                     (float4*)d_ws, n4);

  int nseg = (M + MPB - 1) / MPB;           // 938 @ M=9.6M
  int nmlp = 2000 - (nseg % 2000 == nseg ? nseg : nseg);  // fill to 2000 blocks
  nmlp = 2000 - nseg; if (nmlp < 1) nmlp = 1;
  int ntot = nseg + nmlp;
  hipLaunchKernelGGL(fused_kernel, dim3(ntot), dim3(TPB), 0, stream,
                     lm, pos, idx, gf, w, b, noise, temp,
                     seg_sum, center_raw, out, M, G, nseg, ntot, nmlp);

  int nblk = (3 * G + 255) / 256;
  hipLaunchKernelGGL(norm_kernel, dim3(nblk), dim3(256), 0, stream,
                     seg_sum, center_raw, out, G);
}

// Round 8
// 96.098 us; speedup vs baseline: 1.6461x; 1.1158x over previous
//
#include <hip/hip_runtime.h>
#include <math.h>

static constexpr int CHUNK = 8;           // members per thread (seg path)
static constexpr int TPB   = 256;         // threads per block
static constexpr int MPB   = TPB * CHUNK; // 2048 members per seg block
static constexpr int LOCAL_BINS = 640;    // LDS bins cap (span/block ~43 typical)
static constexpr int ROWS_PER_BLOCK = 32; // mlp: 4 waves x 8 rows (2 quads/wave)

// ---------------------------------------------------------------------------
// Workspace zero (rocclr fillBufferAligned is slow for small fills).
// ---------------------------------------------------------------------------
__global__ __launch_bounds__(256)
void zero_ws_kernel(float4* __restrict__ ws, int n4) {
  int i = blockIdx.x * blockDim.x + threadIdx.x;
  int stride = gridDim.x * blockDim.x;
  for (; i < n4; i += stride) ws[i] = make_float4(0.f, 0.f, 0.f, 0.f);
}

// ---------------------------------------------------------------------------
// Fused kernel: seg blocks and mlp blocks Bresenham-interleaved (best-measured
// R4 geometry: many small blocks, ~11k-block grid).
//
// seg role: 2048 contiguous members/block, LDS bins, 2 barriers. Interior
//   segments -> plain store (exclusive by sortedness); 2 edge segments ->
//   HW fp atomic (~9.4k atomics total).
// mlp role: 2 quads (8 rows) per wave; ALL 8 float4 row-loads issued before
//   the two independent 4-stage reduce chains -> 8 outstanding VMEM/lane
//   (double R4's 4) to hide HBM latency by ILP, not just TLP.
// ---------------------------------------------------------------------------
__global__ __launch_bounds__(TPB)
void fused_kernel(const float* __restrict__ lm,
                  const float* __restrict__ pos,
                  const int*   __restrict__ idx,
                  const float* __restrict__ gf,
                  const float* __restrict__ w,
                  const float* __restrict__ bptr,
                  const float* __restrict__ noise,
                  const int*   __restrict__ temp_ptr,
                  float* __restrict__ seg_sum,     // [G]
                  float* __restrict__ center_raw,  // [3G]
                  float* __restrict__ out,         // [5G]
                  int M, int G, int nseg, int ntot) {
  __shared__ float bins[LOCAL_BINS * 4];

  long long r = blockIdx.x;
  int segcum  = (int)((r * (long long)nseg) / ntot);
  int segcum1 = (int)(((r + 1) * (long long)nseg) / ntot);

  if (segcum1 != segcum) {
    // ---------------- seg role ----------------
    int blockBase = segcum * MPB;
    if (blockBase >= M) return;
    int blockEnd = min(blockBase + MPB, M);
    int g_first = idx[blockBase];
    int g_last  = idx[blockEnd - 1];
    int span    = g_last - g_first + 1;
    int nbins   = min(span, LOCAL_BINS);

    for (int i = threadIdx.x; i < nbins * 4; i += TPB) bins[i] = 0.f;
    __syncthreads();

    int base = blockBase + threadIdx.x * CHUNK;
    if (base < M) {
      auto flush = [&](int g, float se, float sx, float sy, float sz) {
        int off = g - g_first;
        if (off < LOCAL_BINS) {
          unsafeAtomicAdd(&bins[off*4+0], se);
          unsafeAtomicAdd(&bins[off*4+1], sx);
          unsafeAtomicAdd(&bins[off*4+2], sy);
          unsafeAtomicAdd(&bins[off*4+3], sz);
        } else {             // span-overflow fallback (statistically ~never)
          unsafeAtomicAdd(&seg_sum[g], se);
          unsafeAtomicAdd(&center_raw[3*g+0], sx);
          unsafeAtomicAdd(&center_raw[3*g+1], sy);
          unsafeAtomicAdd(&center_raw[3*g+2], sz);
        }
      };

      if (base + CHUNK <= M) {
        const int4*   i4 = (const int4*)(idx + base);
        const float4* l4 = (const float4*)(lm + base);
        const float4* p4 = (const float4*)(pos + (size_t)base * 3);
        int4 ia = i4[0], ic = i4[1];
        float4 la = l4[0], lc = l4[1];
        float4 pA = p4[0], pB = p4[1], pC = p4[2],
               pD = p4[3], pE = p4[4], pF = p4[5];
        int   ib[CHUNK] = {ia.x,ia.y,ia.z,ia.w, ic.x,ic.y,ic.z,ic.w};
        float eb[CHUNK];
        eb[0]=__expf(la.x); eb[1]=__expf(la.y); eb[2]=__expf(la.z); eb[3]=__expf(la.w);
        eb[4]=__expf(lc.x); eb[5]=__expf(lc.y); eb[6]=__expf(lc.z); eb[7]=__expf(lc.w);
        float pb[CHUNK*3] = {pA.x,pA.y,pA.z,pA.w, pB.x,pB.y,pB.z,pB.w,
                             pC.x,pC.y,pC.z,pC.w, pD.x,pD.y,pD.z,pD.w,
                             pE.x,pE.y,pE.z,pE.w, pF.x,pF.y,pF.z,pF.w};

        if (ib[0] == ib[CHUNK-1]) {
          // fast path (~85%): whole chunk in one segment
          float se = 0.f, sx = 0.f, sy = 0.f, sz = 0.f;
          #pragma unroll
          for (int j = 0; j < CHUNK; j++) {
            se += eb[j];
            sx += pb[3*j+0] * eb[j];
            sy += pb[3*j+1] * eb[j];
            sz += pb[3*j+2] * eb[j];
          }
          flush(ib[0], se, sx, sy, sz);
        } else {
          int cur = ib[0];
          float se = 0.f, sx = 0.f, sy = 0.f, sz = 0.f;
          #pragma unroll
          for (int j = 0; j < CHUNK; j++) {
            if (ib[j] != cur) {
              flush(cur, se, sx, sy, sz);
              cur = ib[j]; se = 0.f; sx = 0.f; sy = 0.f; sz = 0.f;
            }
            se += eb[j];
            sx += pb[3*j+0] * eb[j];
            sy += pb[3*j+1] * eb[j];
            sz += pb[3*j+2] * eb[j];
          }
          flush(cur, se, sx, sy, sz);
        }
      } else {
        // ragged tail chunk (last block only)
        int nj = M - base;
        int cur = idx[base];
        float se = 0.f, sx = 0.f, sy = 0.f, sz = 0.f;
        for (int j = 0; j < nj; j++) {
          int g = idx[base + j];
          float e = __expf(lm[base + j]);
          if (g != cur) {
            flush(cur, se, sx, sy, sz);
            cur = g; se = 0.f; sx = 0.f; sy = 0.f; sz = 0.f;
          }
          se += e;
          sx += pos[(size_t)(base+j)*3+0] * e;
          sy += pos[(size_t)(base+j)*3+1] * e;
          sz += pos[(size_t)(base+j)*3+2] * e;
        }
        flush(cur, se, sx, sy, sz);
      }
    }
    __syncthreads();

    for (int i = threadIdx.x; i < nbins; i += TPB) {
      int g = g_first + i;
      float s0 = bins[i*4+0], s1 = bins[i*4+1], s2 = bins[i*4+2], s3 = bins[i*4+3];
      if (g == g_first || g == g_last) {
        unsafeAtomicAdd(&seg_sum[g], s0);
        unsafeAtomicAdd(&center_raw[3*g+0], s1);
        unsafeAtomicAdd(&center_raw[3*g+1], s2);
        unsafeAtomicAdd(&center_raw[3*g+2], s3);
      } else {
        seg_sum[g] = s0;
        center_raw[3*g+0] = s1;
        center_raw[3*g+1] = s2;
        center_raw[3*g+2] = s3;
      }
    }
  } else {
    // ---------------- mlp role: 2 quads per wave ----------------
    int mb   = (int)(r - segcum);
    int wid  = threadIdx.x >> 6;
    int lane = threadIdx.x & 63;
    int sub  = lane & 15;        // lane within 16-lane row group
    int rg   = lane >> 4;        // row within quad

    int row0 = (mb * 4 + wid) * 8;      // this wave's octet
    int rowA = row0 + rg;
    int rowB = row0 + 4 + rg;

    const float4* w4 = (const float4*)w;
    float4 wv0 = w4[sub +  0], wv1 = w4[sub + 16],
           wv2 = w4[sub + 32], wv3 = w4[sub + 48];

    float dA = 0.f, dB = 0.f;
    if (rowA < G) {
      const float4* ga = (const float4*)(gf + (size_t)rowA * 256);
      const float4* gb = (const float4*)(gf + (size_t)rowB * 256);
      // issue all 8 loads before any use: 8 outstanding VMEM per lane
      float4 a0 = ga[sub +  0], a1 = ga[sub + 16],
             a2 = ga[sub + 32], a3 = ga[sub + 48];
      float4 b0 = gb[sub +  0], b1 = gb[sub + 16],
             b2 = gb[sub + 32], b3 = gb[sub + 48];
      dA  = a0.x*wv0.x + a0.y*wv0.y + a0.z*wv0.z + a0.w*wv0.w;
      dA += a1.x*wv1.x + a1.y*wv1.y + a1.z*wv1.z + a1.w*wv1.w;
      dA += a2.x*wv2.x + a2.y*wv2.y + a2.z*wv2.z + a2.w*wv2.w;
      dA += a3.x*wv3.x + a3.y*wv3.y + a3.z*wv3.z + a3.w*wv3.w;
      dB  = b0.x*wv0.x + b0.y*wv0.y + b0.z*wv0.z + b0.w*wv0.w;
      dB += b1.x*wv1.x + b1.y*wv1.y + b1.z*wv1.z + b1.w*wv1.w;
      dB += b2.x*wv2.x + b2.y*wv2.y + b2.z*wv2.z + b2.w*wv2.w;
      dB += b3.x*wv3.x + b3.y*wv3.y + b3.z*wv3.z + b3.w*wv3.w;
    }
    #pragma unroll
    for (int m = 8; m >= 1; m >>= 1) {
      dA += __shfl_xor(dA, m, 64);
      dB += __shfl_xor(dB, m, 64);
    }

    if (sub == 0 && rowA < G) {
      float bb = bptr[0];
      int iv = temp_ptr[0];
      float tT = (iv > -(1 << 23) && iv < (1 << 23)) ? (float)iv : __int_as_float(iv);

      float logitA = 8.8f * tanhf(dA + bb);
      float nA = noise[rowA];
      float xA = (logitA + (logf(nA) - log1pf(-nA))) / tT;
      out[rowA]     = fminf(xA, 0.f) - log1pf(expf(-fabsf(xA)));
      out[G + rowA] = logitA;

      if (rowB < G) {
        float logitB = 8.8f * tanhf(dB + bb);
        float nB = noise[rowB];
        float xB = (logitB + (logf(nB) - log1pf(-nB))) / tT;
        out[rowB]     = fminf(xB, 0.f) - log1pf(expf(-fabsf(xB)));
        out[G + rowB] = logitB;
      }
    }
  }
}

// ---------------------------------------------------------------------------
// Center normalize: out[2G + i] = center_raw[i] / seg_sum[i/3] (0 if empty).
// ---------------------------------------------------------------------------
__global__ __launch_bounds__(256)
void norm_kernel(const float* __restrict__ seg_sum,
                 const float* __restrict__ center_raw,
                 float* __restrict__ out, int G) {
  int i = blockIdx.x * blockDim.x + threadIdx.x;
  int n = 3 * G;
  if (i < n) {
    int g = i / 3;
    float s = seg_sum[g];
    float inv = (s > 0.f) ? (1.f / s) : 0.f;
    out[(size_t)2 * G + i] = center_raw[i] * inv;
  }
}

extern "C" void kernel_launch(void* const* d_in, const int* in_sizes, int n_in,
                              void* d_out, int out_size, void* d_ws, size_t ws_size,
                              hipStream_t stream) {
  const float* gf    = (const float*)d_in[0];
  const float* pos   = (const float*)d_in[1];
  const float* lm    = (const float*)d_in[2];
  const int*   idx   = (const int*)  d_in[3];
  const float* w     = (const float*)d_in[4];
  const float* b     = (const float*)d_in[5];
  const float* noise = (const float*)d_in[6];
  const int*   temp  = (const int*)  d_in[7];
  float* out = (float*)d_out;

  int G = in_sizes[6];
  int M = in_sizes[3];

  float* seg_sum    = (float*)d_ws;
  float* center_raw = seg_sum + G;

  int n4 = (4 * G) / 4;
  hipLaunchKernelGGL(zero_ws_kernel, dim3(784), dim3(256), 0, stream,
                     (float4*)d_ws, n4);

  int nseg = (M + MPB - 1) / MPB;                          // 4688
  int nmlp = (G + ROWS_PER_BLOCK - 1) / ROWS_PER_BLOCK;    // 6250
  int ntot = nseg + nmlp;
  hipLaunchKernelGGL(fused_kernel, dim3(ntot), dim3(TPB), 0, stream,
                     lm, pos, idx, gf, w, b, noise, temp,
                     seg_sum, center_raw, out, M, G, nseg, ntot);

  int nblk = (3 * G + 255) / 256;
  hipLaunchKernelGGL(norm_kernel, dim3(nblk), dim3(256), 0, stream,
                     seg_sum, center_raw, out, G);
}